// Round 1
// baseline (160.138 us; speedup 1.0000x reference)
//
#include <hip/hip_runtime.h>
#include <stdint.h>

#define MROWS 8192
#define KDIM  512

typedef __attribute__((ext_vector_type(8))) short short8;
typedef __attribute__((ext_vector_type(4))) float f32x4;

#if __has_builtin(__builtin_amdgcn_exp2f)
#define EXP2F(x) __builtin_amdgcn_exp2f(x)
#else
#define EXP2F(x) exp2f(x)
#endif

#define GL2LDS(gp, lp) __builtin_amdgcn_global_load_lds( \
    (__attribute__((address_space(1))) void*)(gp),       \
    (__attribute__((address_space(3))) void*)(lp), 16, 0, 0)

__device__ inline unsigned short f2bf_rne(float f) {
  unsigned u = __builtin_bit_cast(unsigned, f);
  unsigned r = 0x7FFFu + ((u >> 16) & 1u);
  return (unsigned short)((u + r) >> 16);
}

// ---------------------------------------------------------------------------
// Kernel 1: cast X (fp32 -> bf16 in ws), per-row squared norm, and
// deterministic block-partial reductions for sigma^2 (column sums + sum of sq).
// 128 blocks x 256 threads; block handles 64 rows, each wave 16 rows.
// ---------------------------------------------------------------------------
__global__ __launch_bounds__(256) void k_prep(
    const float* __restrict__ X, unsigned short* __restrict__ Xb,
    float* __restrict__ sq, float* __restrict__ svec_part,
    float* __restrict__ sumsq_part) {
  __shared__ float ssv[4][512];
  __shared__ float ssq[4];
  const int tid = threadIdx.x, lane = tid & 63, w = tid >> 6;
  const int b = blockIdx.x;

  float ca[8] = {0.f, 0.f, 0.f, 0.f, 0.f, 0.f, 0.f, 0.f};
  float lss = 0.f;

  for (int rr = 0; rr < 16; ++rr) {
    const int row = b * 64 + w * 16 + rr;
    const float4* xr = (const float4*)(X + (size_t)row * KDIM);
    float4 v0 = xr[lane];        // cols lane*4 .. +3
    float4 v1 = xr[64 + lane];   // cols 256+lane*4 .. +3

    ushort4 p0, p1;
    p0.x = f2bf_rne(v0.x); p0.y = f2bf_rne(v0.y);
    p0.z = f2bf_rne(v0.z); p0.w = f2bf_rne(v0.w);
    p1.x = f2bf_rne(v1.x); p1.y = f2bf_rne(v1.y);
    p1.z = f2bf_rne(v1.z); p1.w = f2bf_rne(v1.w);
    *(ushort4*)(Xb + (size_t)row * KDIM + lane * 4)       = p0;
    *(ushort4*)(Xb + (size_t)row * KDIM + 256 + lane * 4) = p1;

    float s2 = v0.x*v0.x + v0.y*v0.y + v0.z*v0.z + v0.w*v0.w
             + v1.x*v1.x + v1.y*v1.y + v1.z*v1.z + v1.w*v1.w;
    float rs = s2;
#pragma unroll
    for (int off = 32; off; off >>= 1) rs += __shfl_xor(rs, off, 64);
    if (lane == 0) sq[row] = rs;
    lss += s2;

    ca[0] += v0.x; ca[1] += v0.y; ca[2] += v0.z; ca[3] += v0.w;
    ca[4] += v1.x; ca[5] += v1.y; ca[6] += v1.z; ca[7] += v1.w;
  }

  // deterministic cross-wave column-sum reduction (no float atomics)
#pragma unroll
  for (int i = 0; i < 4; ++i) {
    ssv[w][lane * 4 + i]       = ca[i];
    ssv[w][256 + lane * 4 + i] = ca[4 + i];
  }
  float wsum = lss;
#pragma unroll
  for (int off = 32; off; off >>= 1) wsum += __shfl_xor(wsum, off, 64);
  if (lane == 0) ssq[w] = wsum;
  __syncthreads();

  svec_part[(size_t)b * 512 + tid] =
      ssv[0][tid] + ssv[1][tid] + ssv[2][tid] + ssv[3][tid];
  svec_part[(size_t)b * 512 + 256 + tid] =
      ssv[0][tid + 256] + ssv[1][tid + 256] + ssv[2][tid + 256] + ssv[3][tid + 256];
  if (tid == 0) sumsq_part[b] = ssq[0] + ssq[1] + ssq[2] + ssq[3];
}

// ---------------------------------------------------------------------------
// Kernel 2: sigma^2 = ALPHA * (2*sum(sq)/m - 2*||sum_i x_i||^2 / m^2)
// scale = log2(e) / (2*sigma^2)   (out = exp2(-d2*scale))
// ---------------------------------------------------------------------------
__global__ __launch_bounds__(256) void k_sigma(
    const float* __restrict__ svec_part, const float* __restrict__ sumsq_part,
    float* __restrict__ scale) {
  __shared__ float red[4];
  const int tid = threadIdx.x, lane = tid & 63, w = tid >> 6;
  float s1 = 0.f, s2 = 0.f;
  for (int b = 0; b < 128; ++b) {
    s1 += svec_part[(size_t)b * 512 + tid];
    s2 += svec_part[(size_t)b * 512 + 256 + tid];
  }
  float ss = s1 * s1 + s2 * s2;
#pragma unroll
  for (int off = 32; off; off >>= 1) ss += __shfl_xor(ss, off, 64);
  if (lane == 0) red[w] = ss;
  __syncthreads();
  if (tid == 0) {
    float sst = red[0] + red[1] + red[2] + red[3];
    float sumsq = 0.f;
    for (int b = 0; b < 128; ++b) sumsq += sumsq_part[b];
    const float m = (float)MROWS;
    float meand2 = 2.f * sumsq / m - 2.f * sst / (m * m);
    float sigma2 = 1.0f * meand2;  // ALPHA = 1.0
    scale[0] = 1.4426950408889634f / (2.f * sigma2);
  }
}

// ---------------------------------------------------------------------------
// Kernel 3: tiled bf16 MFMA GEMM (gram = Xb * Xb^T) with fused epilogue:
// out = exp2(-max(sq_i + sq_j - 2*gram, 0) * scale)
// 128x128 tile, BK=64, 256 threads (4 waves, 2x2), global_load_lds width 16.
// ---------------------------------------------------------------------------
__global__ __launch_bounds__(256) void k_gemm(
    const unsigned short* __restrict__ Xb, const float* __restrict__ sq,
    const float* __restrict__ scale, float* __restrict__ out) {
  __shared__ unsigned short As[128 * 64];
  __shared__ unsigned short Bs[128 * 64];
  const int tid = threadIdx.x, lane = tid & 63, w = tid >> 6;

  // XCD-aware swizzle: nwg = 4096 (divisible by 8)
  int wg = blockIdx.x;
  wg = (wg & 7) * 512 + (wg >> 3);
  const int bi = wg >> 6, bj = wg & 63;
  const int wr = w >> 1, wc = w & 1;

  f32x4 acc[4][4] = {};

  // per-lane global staging address pieces: lane covers row (lane>>3), cols (lane&7)*8
  const unsigned short* baseA =
      Xb + (size_t)(bi * 128 + (lane >> 3)) * KDIM + (lane & 7) * 8;
  const unsigned short* baseB =
      Xb + (size_t)(bj * 128 + (lane >> 3)) * KDIM + (lane & 7) * 8;

  for (int kt = 0; kt < 8; ++kt) {
#pragma unroll
    for (int c4 = 0; c4 < 4; ++c4) {
      const int chunk = w * 4 + c4;  // 16 chunks of 8 rows x 64 cols
      GL2LDS(baseA + (size_t)chunk * 8 * KDIM + kt * 64, &As[chunk * 512]);
      GL2LDS(baseB + (size_t)chunk * 8 * KDIM + kt * 64, &Bs[chunk * 512]);
    }
    __syncthreads();
#pragma unroll
    for (int ks = 0; ks < 2; ++ks) {
      short8 a[4], b[4];
#pragma unroll
      for (int mm = 0; mm < 4; ++mm)
        a[mm] = *(const short8*)&As[(wr * 64 + mm * 16 + (lane & 15)) * 64 +
                                    ks * 32 + (lane >> 4) * 8];
#pragma unroll
      for (int n = 0; n < 4; ++n)
        b[n] = *(const short8*)&Bs[(wc * 64 + n * 16 + (lane & 15)) * 64 +
                                   ks * 32 + (lane >> 4) * 8];
#pragma unroll
      for (int mm = 0; mm < 4; ++mm)
#pragma unroll
        for (int n = 0; n < 4; ++n)
          acc[mm][n] = __builtin_amdgcn_mfma_f32_16x16x32_bf16(
              a[mm], b[n], acc[mm][n], 0, 0, 0);
    }
    __syncthreads();
  }

  // epilogue
  const float cs = scale[0];
  const int r0 = bi * 128 + wr * 64 + (lane >> 4) * 4;
  const int c0 = bj * 128 + wc * 64 + (lane & 15);
  float srow[4][4];
#pragma unroll
  for (int mm = 0; mm < 4; ++mm)
#pragma unroll
    for (int r = 0; r < 4; ++r) srow[mm][r] = sq[r0 + mm * 16 + r];
  float scol[4];
#pragma unroll
  for (int n = 0; n < 4; ++n) scol[n] = sq[c0 + n * 16];

#pragma unroll
  for (int mm = 0; mm < 4; ++mm) {
#pragma unroll
    for (int r = 0; r < 4; ++r) {
      const size_t rowoff = (size_t)(r0 + mm * 16 + r) * MROWS;
#pragma unroll
      for (int n = 0; n < 4; ++n) {
        float d2 = srow[mm][r] + scol[n] - 2.f * acc[mm][n][r];
        d2 = fmaxf(d2, 0.f);
        out[rowoff + c0 + n * 16] = EXP2F(-d2 * cs);
      }
    }
  }
}

// ---------------------------------------------------------------------------
extern "C" void kernel_launch(void* const* d_in, const int* in_sizes, int n_in,
                              void* d_out, int out_size, void* d_ws,
                              size_t ws_size, hipStream_t stream) {
  (void)in_sizes; (void)n_in; (void)out_size; (void)ws_size;
  const float* X = (const float*)d_in[0];
  float* out = (float*)d_out;
  char* ws = (char*)d_ws;

  unsigned short* Xb  = (unsigned short*)ws;                    // 8 MB bf16 copy
  float* sq           = (float*)(ws + 8388608);                 // 32 KB row norms
  float* svec_part    = (float*)(ws + 8388608 + 32768);         // 128*512*4 = 256 KB
  float* sumsq_part   = (float*)(ws + 8388608 + 32768 + 262144);// 512 B
  float* scale        = (float*)(ws + 8388608 + 32768 + 262144 + 512);

  hipLaunchKernelGGL(k_prep, dim3(128), dim3(256), 0, stream,
                     X, Xb, sq, svec_part, sumsq_part);
  hipLaunchKernelGGL(k_sigma, dim3(1), dim3(256), 0, stream,
                     svec_part, sumsq_part, scale);
  hipLaunchKernelGGL(k_gemm, dim3(4096), dim3(256), 0, stream,
                     Xb, sq, scale, out);
}